// Round 1
// baseline (110.195 us; speedup 1.0000x reference)
//
#include <hip/hip_runtime.h>

// out0 = 0.5*(1 + cos(th)*cos(x0) - sin(th)*sin(x0)*sin(x1))
// out1 = 0.5*(1 + cos(x0)*cos(x1))
// Derived in closed form from the 2-qubit RY/CNOT/RY circuit (see analysis).
// Memory-bound: 16 B in + 16 B out per thread (2 batch elements per thread).

__global__ __launch_bounds__(256) void qc_kernel(
    const float4* __restrict__ x4,
    const float* __restrict__ theta,
    float4* __restrict__ out4,
    int n4)
{
    int i = blockIdx.x * blockDim.x + threadIdx.x;
    if (i >= n4) return;

    // theta is wave-uniform; broadcast load + 2 transcendentals
    float th = theta[0];
    float ct = __cosf(th);
    float st = __sinf(th);

    float4 v = x4[i];  // (x0, x1, x0', x1') — two batch elements

    float s0 = __sinf(v.x), c0 = __cosf(v.x);
    float s1 = __sinf(v.y), c1 = __cosf(v.y);
    float s2 = __sinf(v.z), c2 = __cosf(v.z);
    float s3 = __sinf(v.w), c3 = __cosf(v.w);

    float4 o;
    o.x = 0.5f * (1.0f + ct * c0 - st * s0 * s1);
    o.y = 0.5f * (1.0f + c0 * c1);
    o.z = 0.5f * (1.0f + ct * c2 - st * s2 * s3);
    o.w = 0.5f * (1.0f + c2 * c3);

    out4[i] = o;
}

extern "C" void kernel_launch(void* const* d_in, const int* in_sizes, int n_in,
                              void* d_out, int out_size, void* d_ws, size_t ws_size,
                              hipStream_t stream) {
    const float* x     = (const float*)d_in[0];  // [B,2] flat
    const float* theta = (const float*)d_in[1];  // [1]
    float* out         = (float*)d_out;          // [B,2] flat

    int n  = in_sizes[0];      // total floats = 2*B (divisible by 4)
    int n4 = n / 4;

    const int block = 256;
    int grid = (n4 + block - 1) / block;

    qc_kernel<<<grid, block, 0, stream>>>(
        (const float4*)x, theta, (float4*)out, n4);
}